// Round 14
// baseline (1564.586 us; speedup 1.0000x reference)
//
#include <hip/hip_runtime.h>
#include <cstdint>
#include <cstddef>

typedef __bf16 bf16;
typedef __bf16 bf16x8 __attribute__((ext_vector_type(8)));
typedef float  f32x4  __attribute__((ext_vector_type(4)));

#define DEVI static __device__ __forceinline__

DEVI float fsigmoid(float x) { return 1.0f / (1.0f + __expf(-x)); }
DEVI float fsilu(float x)    { return x / (1.0f + __expf(-x)); }

DEVI unsigned short b16bits(float v) { bf16 h = (bf16)v; return __builtin_bit_cast(unsigned short, h); }
DEVI float lo16f(unsigned int w) { return __builtin_bit_cast(float, w << 16); }
DEVI float hi16f(unsigned int w) { return __builtin_bit_cast(float, w & 0xffff0000u); }

DEVI float waveRedSum(float v) {
#pragma unroll
  for (int o = 32; o > 0; o >>= 1) v += __shfl_xor(v, o, 64);
  return v;
}
DEVI float waveRedMax(float v) {
#pragma unroll
  for (int o = 32; o > 0; o >>= 1) v = fmaxf(v, __shfl_xor(v, o, 64));
  return v;
}

// T1: bijective XCD-aware block swizzle (m204).
DEVI void xcd_swizzle(int& bx, int& by) {
  const int gx = gridDim.x, gy = gridDim.y;
  const int nwg = gx * gy;
  const int flat = blockIdx.y * gx + blockIdx.x;
  const int xcd = flat & 7;
  const int rem = nwg & 7;
  const int q = nwg >> 3;
  const int base = (xcd < rem) ? xcd * (q + 1) : rem * (q + 1) + (xcd - rem) * q;
  const int swz = base + (flat >> 3);
  bx = swz % gx;
  by = swz / gx;
}

struct alignas(8) B4 { bf16 x, y, z, w; };

// ---------------- diagnostic fallback ----------------
__global__ __launch_bounds__(256) void k_copyout(const float* __restrict__ x, float* __restrict__ o)
{
  const long i = (long)blockIdx.x * 256 + threadIdx.x;
  ((float4*)o)[i] = ((const float4*)x)[i];
}

// ---------------- LN stats ----------------
__global__ __launch_bounds__(256) void k_lnstats(const float* __restrict__ x, float* __restrict__ stats)
{
  const long t = blockIdx.x;
  const int tid = threadIdx.x;
  const float4 v = ((const float4*)(x + t * 1024))[tid];
  float s  = v.x + v.y + v.z + v.w;
  float s2 = v.x * v.x + v.y * v.y + v.z * v.z + v.w * v.w;
  __shared__ float red[2][4];
  s = waveRedSum(s);
  s2 = waveRedSum(s2);
  const int wv = tid >> 6, ln = tid & 63;
  if (ln == 0) { red[0][wv] = s; red[1][wv] = s2; }
  __syncthreads();
  if (tid == 0) {
    s  = red[0][0] + red[0][1] + red[0][2] + red[0][3];
    s2 = red[1][0] + red[1][1] + red[1][2] + red[1][3];
    const float mu  = s * (1.0f / 1024.0f);
    const float var = s2 * (1.0f / 1024.0f) - mu * mu;
    stats[2 * t]     = mu;
    stats[2 * t + 1] = rsqrtf(var + 1e-5f);
  }
}

// ---------------- f32 -> bf16 convert ----------------
__global__ __launch_bounds__(256) void k_cvt(const float* __restrict__ in, bf16* __restrict__ out, int n4)
{
  const int i = blockIdx.x * 256 + threadIdx.x;
  if (i >= n4) return;
  const float4 v = ((const float4*)in)[i];
  B4 h; h.x = (bf16)v.x; h.y = (bf16)v.y; h.z = (bf16)v.z; h.w = (bf16)v.w;
  ((B4*)out)[i] = h;
}

// ---------------- EMA coefficients ----------------
__global__ __launch_bounds__(256) void k_ema_coeff(
    const float* __restrict__ de, const float* __restrict__ al,
    const float* __restrict__ be, const float* __restrict__ ga,
    float* __restrict__ qv, float* __restrict__ cv)
{
  const int i = blockIdx.x * 256 + threadIdx.x;
  const int d = i >> 4, n = i & 15;
  const float p = 1.0f / (1.0f + expf(-de[i]));
  const float a = 1.0f / (1.0f + expf(-al[i]));
  qv[n * 1024 + d] = 1.0f - p * a;
  cv[n * 1024 + d] = p * be[i] * ga[i] * 0.25f;
}

// ---------------- EMA pass 1 ----------------
__global__ __launch_bounds__(256) void k_ema_scan1(
    const float* __restrict__ x, const float* __restrict__ stats,
    const float* __restrict__ lnw, const float* __restrict__ lnb,
    const float* __restrict__ qv, float* __restrict__ scan)
{
  const int d = blockIdx.x * 256 + threadIdx.x;
  const int b = blockIdx.y, c = blockIdx.z;
  float q[16], s[16];
#pragma unroll
  for (int n = 0; n < 16; ++n) { q[n] = qv[n * 1024 + d]; s[n] = 0.0f; }
  const float wd = lnw[d], bd = lnb[d];
  const float* xp = x + (long)b * 1024 + d;
  const int l0 = c * 128;
  for (int j0 = 0; j0 < 128; j0 += 8) {
    float xr[8]; float2 st[8];
#pragma unroll
    for (int i = 0; i < 8; ++i) {
      const int l = l0 + j0 + i;
      xr[i] = xp[(long)l * 8192];
      st[i] = ((const float2*)stats)[(long)l * 8 + b];
    }
#pragma unroll
    for (int i = 0; i < 8; ++i) {
      const float xv = (xr[i] - st[i].x) * st[i].y * wd + bd;
#pragma unroll
      for (int n = 0; n < 16; ++n) s[n] = fmaf(q[n], s[n], xv);
    }
  }
  float* sp = scan + ((((long)c * 8 + b) * 1024) + d) * 16;
#pragma unroll
  for (int n = 0; n < 16; ++n) sp[n] = s[n];
}

// ---------------- EMA pass 2 ----------------
__global__ __launch_bounds__(256) void k_ema_scan2(
    const float* __restrict__ qv, float* __restrict__ scan)
{
  const int i = blockIdx.x * 256 + threadIdx.x;
  const int n = i & 15, d = (i >> 4) & 1023, b = i >> 14;
  const float q = qv[n * 1024 + d];
  const float q2 = q * q, q4 = q2 * q2, q8 = q4 * q4;
  const float q16 = q8 * q8, q32 = q16 * q16, q64 = q32 * q32, q128 = q64 * q64;
  float carry = 0.0f;
#pragma unroll
  for (int c = 0; c < 16; ++c) {
    const long off = ((((long)c * 8 + b) * 1024) + d) * 16 + n;
    const float t = scan[off];
    scan[off] = carry;
    carry = fmaf(q128, carry, t);
  }
}

// ---------------- EMA pass 3 ----------------
__global__ __launch_bounds__(256) void k_ema_apply(
    const float* __restrict__ x, const float* __restrict__ stats,
    const float* __restrict__ lnw, const float* __restrict__ lnb,
    const float* __restrict__ qv, const float* __restrict__ cv,
    const float* __restrict__ omega, const float* __restrict__ scan,
    bf16* __restrict__ mx)
{
  const int d = blockIdx.x * 256 + threadIdx.x;
  const int b = blockIdx.y, c = blockIdx.z;
  float q[16], cc[16], s[16];
  const float* sp = scan + ((((long)c * 8 + b) * 1024) + d) * 16;
#pragma unroll
  for (int n = 0; n < 16; ++n) {
    q[n] = qv[n * 1024 + d];
    cc[n] = cv[n * 1024 + d];
    s[n] = sp[n];
  }
  const float om = omega[d], wd = lnw[d], bd = lnb[d];
  const float* xp = x + (long)b * 1024 + d;
  bf16* mp = mx + (long)b * 1024 + d;
  const int l0 = c * 128;
  for (int j0 = 0; j0 < 128; j0 += 8) {
    float xr[8]; float2 st[8];
#pragma unroll
    for (int i = 0; i < 8; ++i) {
      const int l = l0 + j0 + i;
      xr[i] = xp[(long)l * 8192];
      st[i] = ((const float2*)stats)[(long)l * 8 + b];
    }
#pragma unroll
    for (int i = 0; i < 8; ++i) {
      const float xv = (xr[i] - st[i].x) * st[i].y * wd + bd;
      float p0 = 0.f, p1 = 0.f, p2 = 0.f, p3 = 0.f;
#pragma unroll
      for (int n = 0; n < 16; n += 4) {
        s[n]     = fmaf(q[n],     s[n],     xv);
        s[n + 1] = fmaf(q[n + 1], s[n + 1], xv);
        s[n + 2] = fmaf(q[n + 2], s[n + 2], xv);
        s[n + 3] = fmaf(q[n + 3], s[n + 3], xv);
        p0 = fmaf(cc[n],     s[n],     p0);
        p1 = fmaf(cc[n + 1], s[n + 1], p1);
        p2 = fmaf(cc[n + 2], s[n + 2], p2);
        p3 = fmaf(cc[n + 3], s[n + 3], p3);
      }
      const float pre = fmaf(xv, om, (p0 + p1) + (p2 + p3));
      mp[(long)(l0 + j0 + i) * 8192] = (bf16)fsilu(pre);
    }
  }
}

// ---------------- rotary columns ----------------
__global__ __launch_bounds__(64) void k_rotfill(
    const float* __restrict__ rba, const float* __restrict__ rbb,
    bf16* __restrict__ Qp, bf16* __restrict__ Kp)
{
  const int l = blockIdx.x, zi = threadIdx.x;
  const float fr = __expf(-0.14391156831212787f * (float)zi);
  const float pos = (float)l * fr;
  const float sn = sinf(pos), cs = cosf(pos);
  const float a1 = rba[zi], a2 = rba[64 + zi];
  const float b1 = rbb[zi], b2 = rbb[64 + zi];
  const bf16 qa = (bf16)(a1 * cs - a2 * sn);
  const bf16 qb = (bf16)(a2 * cs + a1 * sn);
  const bf16 ka = (bf16)(b1 * cs - b2 * sn);
  const bf16 kb = (bf16)(b2 * cs + b1 * sn);
#pragma unroll
  for (int b = 0; b < 8; ++b) {
    const long base = ((long)b * 2048 + l) * 256;
    Qp[base + 128 + zi] = qa;
    Qp[base + 192 + zi] = qb;
    Kp[base + 128 + zi] = ka;
    Kp[base + 192 + zi] = kb;
  }
}

// ------- row softmax IN-PLACE -------
__global__ __launch_bounds__(256) void k_softmax(float* __restrict__ S)
{
  const long row = blockIdx.x;
  float* sp = S + row * 2048;
  const int tid = threadIdx.x;
  float vals[8];
  float mx = -1e30f;
#pragma unroll
  for (int i = 0; i < 8; ++i) { vals[i] = sp[i * 256 + tid]; mx = fmaxf(mx, vals[i]); }
  __shared__ float red[4];
  mx = waveRedMax(mx);
  const int wv = tid >> 6, ln = tid & 63;
  if (ln == 0) red[wv] = mx;
  __syncthreads();
  mx = fmaxf(fmaxf(red[0], red[1]), fmaxf(red[2], red[3]));
  float sum = 0.f;
#pragma unroll
  for (int i = 0; i < 8; ++i) { vals[i] = __expf(vals[i] - mx); sum += vals[i]; }
  __syncthreads();
  sum = waveRedSum(sum);
  if (ln == 0) red[wv] = sum;
  __syncthreads();
  sum = red[0] + red[1] + red[2] + red[3];
  const float inv = 1.0f / sum;
  bf16* pp = (bf16*)sp;
#pragma unroll
  for (int i = 0; i < 8; ++i) pp[i * 256 + tid] = (bf16)(vals[i] * inv);
}

// ------- V transpose (one M-slice) -------
__global__ __launch_bounds__(1024) void k_vtrans8(
    const bf16* __restrict__ v, bf16* __restrict__ vt, const int loff)
{
  __shared__ bf16 tile[32][33];
  const int l0 = blockIdx.x * 32, h0 = blockIdx.y * 32, b = blockIdx.z;
  const int tx = threadIdx.x, ty = threadIdx.y;
  tile[ty][tx] = v[((long)(l0 + ty) * 8 + b) * 2048 + h0 + tx];
  __syncthreads();
  vt[((long)b * 2048 + h0 + ty) * 2048 + loff + l0 + tx] = tile[tx][ty];
}

DEVI void gload16(const void* g, void* l) {
  __builtin_amdgcn_global_load_lds(
      (__attribute__((address_space(1))) void*)(void*)g,
      (__attribute__((address_space(3))) void*)l, 16, 0, 0);
}

// ========== 128x128 pipelined NT GEMM: 4 LDS buffers, distance-3, counted vmcnt ==========
// Invariant: before any wave computes tile T, it executed a waitcnt retiring its
// own tile-T loads AND passed a barrier (all waves ditto) -> race-free by construction.
// Per iter: STAGE(t+3) [8 loads] -> compute(t) -> vmcnt(16)/8/0 -> barrier.
// EPI: 1 = base proj split epilogue; 3 = PV (*r in-place, row remap); 4 = final.
template<int EPI>
__global__ __launch_bounds__(256) void k_gemm_p3(
    const bf16* __restrict__ A, const bf16* __restrict__ Bm,
    const int K, const int lda, const int ldb,
    const float* __restrict__ bias,
    void* __restrict__ o0, void* __restrict__ o1, void* __restrict__ o2, void* __restrict__ o3,
    const void* __restrict__ e0, const void* __restrict__ e1)
{
  __shared__ alignas(16) bf16 As[4][8192];   // 4 buffers x 16 KiB
  __shared__ alignas(16) bf16 Bs[4][8192];
  const int tid = threadIdx.x;
  const int wave = tid >> 6, lane = tid & 63;
  const int wm = wave >> 1, wn = wave & 1;
  int bx, by;
  xcd_swizzle(bx, by);
  const int tm = by * 128, tn = bx * 128;
  const int fr = lane & 15, kg = lane >> 4;
  const int swR = (fr & 7) << 3;

  f32x4 acc[4][4];
  const f32x4 z4 = {0.0f, 0.0f, 0.0f, 0.0f};
#pragma unroll
  for (int i = 0; i < 4; ++i)
#pragma unroll
    for (int j = 0; j < 4; ++j) acc[i][j] = z4;

  const int srow = wave * 8 + (lane >> 3);
  const int scol = ((lane & 7) ^ (lane >> 3)) * 8;   // T2 pre-swizzled source chunk
  const long arow = (long)(tm + srow);
  const long brow = (long)(tn + srow);

#define STAGE_P3(buf, kt) do { const int k0_ = (kt) << 6;                                   \
    _Pragma("unroll")                                                                        \
    for (int cc_ = 0; cc_ < 4; ++cc_) {                                                      \
      gload16(A  + (arow + cc_ * 32) * lda + k0_ + scol, &As[buf][cc_ * 2048 + wave * 512]); \
      gload16(Bm + (brow + cc_ * 32) * ldb + k0_ + scol, &Bs[buf][cc_ * 2048 + wave * 512]); \
    } } while (0)

  const int nt = K >> 6;   // callers guarantee nt >= 3
  STAGE_P3(0, 0);
  STAGE_P3(1, 1);
  STAGE_P3(2, 2);
  asm volatile("s_waitcnt vmcnt(16)" ::: "memory");   // tile 0 retired; tiles 1,2 in flight
  __syncthreads();

  for (int t = 0; t < nt; ++t) {
    const int cur = t & 3;
    if (t + 3 < nt) STAGE_P3((t + 3) & 3, t + 3);
    const bf16* Ab = &As[cur][0];
    const bf16* Bb = &Bs[cur][0];
    bf16x8 af[2][4], bfv[2][4];
#pragma unroll
    for (int ks = 0; ks < 2; ++ks)
#pragma unroll
      for (int i = 0; i < 4; ++i) {
        af[ks][i]  = *(const bf16x8*)&Ab[(wm * 64 + i * 16 + fr) * 64 + ((ks * 32 + kg * 8) ^ swR)];
        bfv[ks][i] = *(const bf16x8*)&Bb[(wn * 64 + i * 16 + fr) * 64 + ((ks * 32 + kg * 8) ^ swR)];
      }
#pragma unroll
    for (int ks = 0; ks < 2; ++ks)
#pragma unroll
      for (int i = 0; i < 4; ++i)
#pragma unroll
        for (int j = 0; j < 4; ++j)
          acc[i][j] = __builtin_amdgcn_mfma_f32_16x16x32_bf16(af[ks][i], bfv[ks][j], acc[i][j], 0, 0, 0);
    if (t + 1 < nt) {
      if (t + 3 < nt)      asm volatile("s_waitcnt vmcnt(16)" ::: "memory"); // tile t+1 retired
      else if (t + 2 < nt) asm volatile("s_waitcnt vmcnt(8)"  ::: "memory");
      else                 asm volatile("s_waitcnt vmcnt(0)"  ::: "memory");
      __syncthreads();
    }
  }
#undef STAGE_P3

#pragma unroll
  for (int i = 0; i < 4; ++i) {
#pragma unroll
    for (int j = 0; j < 4; ++j) {
#pragma unroll
      for (int rr = 0; rr < 4; ++rr) {
        const int row = tm + wm * 64 + i * 16 + kg * 4 + rr;
        const int col = tn + wn * 64 + j * 16 + fr;
        const float a = acc[i][j][rr];
        if constexpr (EPI == 1) {
          const float tv = a + bias[col];
          if (col < 1024) {
            ((unsigned short*)o0)[((long)row * 1024 + col) * 2] = b16bits(fsigmoid(tv));
          } else if (col < 1152) {
            const int zi = col - 1024;
            const float zval = fsilu(tv);
            const float qq = (zval * ((const float*)e0)[zi] + ((const float*)e1)[zi]) * 0.08838834764831845f;
            const float kk =  zval * ((const float*)e0)[128 + zi] + ((const float*)e1)[128 + zi];
            const long base = ((long)(row & 7) * 2048 + (row >> 3)) * 256 + zi;
            ((bf16*)o2)[base] = (bf16)qq;
            ((bf16*)o3)[base] = (bf16)kk;
          } else if (col < 3200) {
            ((bf16*)o1)[(long)row * 2048 + (col - 1152)] = (bf16)fsilu(tv);
          } else {
            ((unsigned short*)o0)[((long)row * 1024 + (col - 3200)) * 2 + 1] = b16bits(tv);
          }
        } else if constexpr (EPI == 3) {
          const long idx = (long)row * 16384 + col;   // (row*8)*2048 + col
          const float rv = (float)((const bf16*)e0)[idx];
          ((bf16*)o0)[idx] = (bf16)(a * rv);
        } else if constexpr (EPI == 4) {
          const long idx = (long)row * 1024 + col;
          const unsigned int w = ((const unsigned int*)o0)[idx];
          const float uv = lo16f(w), hxv = hi16f(w);
          const float hval = fsilu(hxv + a + bias[col]);
          const float xv = ((const float*)e1)[idx];
          ((float*)o0)[idx] = xv + uv * (hval - xv);
        }
      }
    }
  }
}

// ---------------- 128x128 2-barrier NT GEMM (QK only, K=256) ----------------
template<int EPI>
__global__ __launch_bounds__(256) void k_gemm_bt(
    const bf16* __restrict__ A, const bf16* __restrict__ Bm,
    const int K, const int lda, const int ldb, const int coladd,
    const float* __restrict__ bias,
    void* __restrict__ o0, void* __restrict__ o1, void* __restrict__ o2, void* __restrict__ o3,
    const void* __restrict__ e0, const void* __restrict__ e1, const void* __restrict__ e2)
{
  __shared__ alignas(16) bf16 As[128 * 64];
  __shared__ alignas(16) bf16 Bs[128 * 64];
  const int tid = threadIdx.x;
  const int wave = tid >> 6, lane = tid & 63;
  const int wm = wave >> 1, wn = wave & 1;
  int bx, by;
  xcd_swizzle(bx, by);
  const int tm = by * 128, tn = bx * 128;
  const int fr = lane & 15, kg = lane >> 4;

  f32x4 acc[4][4];
  const f32x4 z4 = {0.0f, 0.0f, 0.0f, 0.0f};
#pragma unroll
  for (int i = 0; i < 4; ++i)
#pragma unroll
    for (int j = 0; j < 4; ++j) acc[i][j] = z4;

  const int srow = wave * 8 + (lane >> 3);
  const int scol = ((lane & 7) ^ (lane >> 3)) * 8;
  const long arow = (long)(tm + srow);
  const long brow = (long)(tn + srow);
  const int swR = (fr & 7) << 3;

  for (int k0 = 0; k0 < K; k0 += 64) {
    __syncthreads();
#pragma unroll
    for (int cc = 0; cc < 4; ++cc) {
      gload16(A + (arow + cc * 32) * lda + k0 + scol, As + cc * 2048 + wave * 512);
      gload16(Bm + (brow + cc * 32) * ldb + k0 + scol, Bs + cc * 2048 + wave * 512);
    }
    __syncthreads();
    bf16x8 af[2][4], bfv[2][4];
#pragma unroll
    for (int ks = 0; ks < 2; ++ks)
#pragma unroll
      for (int i = 0; i < 4; ++i) {
        af[ks][i]  = *(const bf16x8*)&As[(wm * 64 + i * 16 + fr) * 64 + ((ks * 32 + kg * 8) ^ swR)];
        bfv[ks][i] = *(const bf16x8*)&Bs[(wn * 64 + i * 16 + fr) * 64 + ((ks * 32 + kg * 8) ^ swR)];
      }
#pragma unroll
    for (int ks = 0; ks < 2; ++ks)
#pragma unroll
      for (int i = 0; i < 4; ++i)
#pragma unroll
        for (int j = 0; j < 4; ++j)
          acc[i][j] = __builtin_amdgcn_mfma_f32_16x16x32_bf16(af[ks][i], bfv[ks][j], acc[i][j], 0, 0, 0);
  }

#pragma unroll
  for (int i = 0; i < 4; ++i) {
#pragma unroll
    for (int j = 0; j < 4; ++j) {
#pragma unroll
      for (int rr = 0; rr < 4; ++rr) {
        const int row = tm + wm * 64 + i * 16 + kg * 4 + rr;
        const int col = coladd + tn + wn * 64 + j * 16 + fr;
        const float a = acc[i][j][rr];
        if constexpr (EPI == 2) {
          ((float*)o0)[(long)row * 2048 + col] = a;
        }
      }
    }
  }
}

// ---------------- V-proj GEMM with fused-LN A staging ----------------
__global__ __launch_bounds__(256) void k_gemm_lnA(
    const float* __restrict__ x, const float* __restrict__ stats,
    const float* __restrict__ lnw, const float* __restrict__ lnb,
    const bf16* __restrict__ Bm, const float* __restrict__ bias,
    bf16* __restrict__ out)
{
  __shared__ alignas(16) bf16 As[128 * 64];
  __shared__ alignas(16) bf16 Bs[128 * 64];
  __shared__ float smu[128], srs[128];
  const int tid = threadIdx.x;
  const int wave = tid >> 6, lane = tid & 63;
  const int wm = wave >> 1, wn = wave & 1;
  int bx, by;
  xcd_swizzle(bx, by);
  const int tm = by * 128, tn = bx * 128;
  const int fr = lane & 15, kg = lane >> 4;
  if (tid < 128) {
    smu[tid] = stats[2 * (long)(tm + tid)];
    srs[tid] = stats[2 * (long)(tm + tid) + 1];
  }

  f32x4 acc[4][4];
  const f32x4 z4 = {0.0f, 0.0f, 0.0f, 0.0f};
#pragma unroll
  for (int i = 0; i < 4; ++i)
#pragma unroll
    for (int j = 0; j < 4; ++j) acc[i][j] = z4;

  const int srow = wave * 8 + (lane >> 3);
  const int scol = ((lane & 7) ^ (lane >> 3)) * 8;
  const long brow = (long)(tn + srow);
  const int swR = (fr & 7) << 3;
  const int ar = tid & 127, ah = (tid >> 7) * 32;
  const float* xrow = x + (long)(tm + ar) * 1024 + ah;

  for (int k0 = 0; k0 < 1024; k0 += 64) {
    __syncthreads();
#pragma unroll
    for (int cc = 0; cc < 4; ++cc)
      gload16(Bm + (brow + cc * 32) * 1024 + k0 + scol, Bs + cc * 2048 + wave * 512);
    {
      const float mu = smu[ar], rs = srs[ar];
      bf16 tmp[32];
#pragma unroll
      for (int i = 0; i < 8; ++i) {
        const float4 xv = ((const float4*)(xrow + k0))[i];
        const float4 wv = ((const float4*)(lnw + k0 + ah))[i];
        const float4 bv = ((const float4*)(lnb + k0 + ah))[i];
        tmp[i * 4 + 0] = (bf16)((xv.x - mu) * rs * wv.x + bv.x);
        tmp[i * 4 + 1] = (bf16)((xv.y - mu) * rs * wv.y + bv.y);
        tmp[i * 4 + 2] = (bf16)((xv.z - mu) * rs * wv.z + bv.z);
        tmp[i * 4 + 3] = (bf16)((xv.w - mu) * rs * wv.w + bv.w);
      }
      const int sw = (ar & 7) << 3;
#pragma unroll
      for (int i = 0; i < 4; ++i)
        *(bf16x8*)&As[ar * 64 + ((ah + i * 8) ^ sw)] = *(const bf16x8*)&tmp[i * 8];
    }
    __syncthreads();
    bf16x8 af[2][4], bfv[2][4];
#pragma unroll
    for (int ks = 0; ks < 2; ++ks)
#pragma unroll
      for (int i = 0; i < 4; ++i) {
        const int ar2 = wm * 64 + i * 16 + fr;
        af[ks][i]  = *(const bf16x8*)&As[ar2 * 64 + ((ks * 32 + kg * 8) ^ ((ar2 & 7) << 3))];
        bfv[ks][i] = *(const bf16x8*)&Bs[(wn * 64 + i * 16 + fr) * 64 + ((ks * 32 + kg * 8) ^ swR)];
      }
#pragma unroll
    for (int ks = 0; ks < 2; ++ks)
#pragma unroll
      for (int i = 0; i < 4; ++i)
#pragma unroll
        for (int j = 0; j < 4; ++j)
          acc[i][j] = __builtin_amdgcn_mfma_f32_16x16x32_bf16(af[ks][i], bfv[ks][j], acc[i][j], 0, 0, 0);
  }

#pragma unroll
  for (int i = 0; i < 4; ++i)
#pragma unroll
    for (int j = 0; j < 4; ++j)
#pragma unroll
      for (int rr = 0; rr < 4; ++rr) {
        const int row = tm + wm * 64 + i * 16 + kg * 4 + rr;
        const int col = tn + wn * 64 + j * 16 + fr;
        out[(long)row * 2048 + col] = (bf16)fsilu(acc[i][j][rr] + bias[col]);
      }
}

extern "C" void kernel_launch(void* const* d_in, const int* in_sizes, int n_in,
                              void* d_out, int out_size, void* d_ws, size_t ws_size,
                              hipStream_t stream)
{
  const float* x    = (const float*)d_in[0];
  const float* ln_w = (const float*)d_in[1];
  const float* ln_b = (const float*)d_in[2];
  const float* v_w  = (const float*)d_in[3];
  const float* v_b  = (const float*)d_in[4];
  const float* mx_w = (const float*)d_in[5];
  const float* mx_b = (const float*)d_in[6];
  const float* h_w  = (const float*)d_in[7];
  const float* h_b  = (const float*)d_in[8];
  const float* qk_g = (const float*)d_in[9];
  const float* qk_b = (const float*)d_in[10];
  const float* e_de = (const float*)d_in[11];
  const float* e_al = (const float*)d_in[12];
  const float* e_be = (const float*)d_in[13];
  const float* e_ga = (const float*)d_in[14];
  const float* e_om = (const float*)d_in[15];
  const float* rb_a = (const float*)d_in[16];
  const float* rb_b = (const float*)d_in[17];

  const size_t MiB = 1048576UL;
  if (ws_size < 160 * MiB) {
    k_copyout<<<16384, 256, 0, stream>>>(x, (float*)d_out);
    return;
  }

  // Static map, peak exactly 160 MiB:
  char* ws = (char*)d_ws;
  bf16*  rbuf  = (bf16*)(ws + 0 * MiB);
  bf16*  v_t   = (bf16*)(ws + 64 * MiB);
  bf16*  mxw_h = (bf16*)(ws + 64 * MiB);
  bf16*  mxb   = (bf16*)(ws + 73 * MiB);
  float* qv    = (float*)(ws + 105 * MiB);
  float* cv    = (float*)(ws + 105 * MiB + 65536);
  bf16*  Qp    = (bf16*)(ws + 128 * MiB);
  bf16*  hw_h  = (bf16*)(ws + 128 * MiB);
  bf16*  Kp    = (bf16*)(ws + 136 * MiB);
  float* Sbuf  = (float*)(ws + 144 * MiB);
  bf16*  vw_h  = (bf16*)(ws + 144 * MiB);
  float* scanb = (float*)(ws + 148 * MiB);
  bf16*  vbufe = (bf16*)(ws + 148 * MiB);
  float* stats = (float*)(ws + 156 * MiB);

  k_lnstats<<<16384, 256, 0, stream>>>(x, stats);
  k_cvt<<<2048, 256, 0, stream>>>(v_w, vw_h, 524288);
  k_cvt<<<4224, 256, 0, stream>>>(mx_w, mxw_h, 1081344);
  k_ema_coeff<<<64, 256, 0, stream>>>(e_de, e_al, e_be, e_ga, qv, cv);

  // EMA via 3-pass chunked parallel scan
  k_ema_scan1<<<dim3(4, 8, 16), 256, 0, stream>>>(x, stats, ln_w, ln_b, qv, scanb);
  k_ema_scan2<<<512, 256, 0, stream>>>(qv, scanb);
  k_ema_apply<<<dim3(4, 8, 16), 256, 0, stream>>>(x, stats, ln_w, ln_b, qv, cv, e_om, scanb, mxb);

  // base = mx @ mx_w^T + mx_b (pipelined 128^2, nt=16):
  // u -> d_out.lo16, z -> Qp/Kp, r -> rbuf, hx -> d_out.hi16
  k_gemm_p3<1><<<dim3(33, 128, 1), 256, 0, stream>>>(mxb, mxw_h, 1024, 1024, 1024,
      mx_b, d_out, (void*)rbuf, (void*)Qp, (void*)Kp, (const void*)qk_g, (const void*)qk_b);
  k_rotfill<<<2048, 64, 0, stream>>>(rb_a, rb_b, Qp, Kp);

  // V-proj in 8 M-slices, each transposed into v_t at l-offset e*256
  for (int e = 0; e < 8; ++e) {
    k_gemm_lnA<<<dim3(16, 16, 1), 256, 0, stream>>>(x + (long)e * 2048 * 1024, stats + (long)e * 4096,
        ln_w, ln_b, vw_h, v_b, vbufe);
    k_vtrans8<<<dim3(8, 64, 8), dim3(32, 32), 0, stream>>>(vbufe, v_t, e * 256);
  }

  // attention per full batch: QK (2-barrier, nt=4) -> softmax -> PV (pipelined, nt=32)
  for (int b = 0; b < 8; ++b) {
    const bf16* Ab = Qp + (long)b * 524288;
    const bf16* Bb = Kp + (long)b * 524288;
    k_gemm_bt<2><<<dim3(16, 16, 1), 256, 0, stream>>>(Ab, Bb, 256, 256, 256, 0,
        nullptr, (void*)Sbuf, nullptr, nullptr, nullptr, nullptr, nullptr, nullptr);
    k_softmax<<<2048, 256, 0, stream>>>(Sbuf);
    bf16* hrp = rbuf + (long)b * 2048;
    k_gemm_p3<3><<<dim3(16, 16, 1), 256, 0, stream>>>((const bf16*)Sbuf, v_t + (long)b * 4194304,
        2048, 4096, 2048, nullptr, (void*)hrp, nullptr, nullptr, nullptr, (const void*)hrp, nullptr);
  }

  // h_w -> bf16 into dead Qp slot
  k_cvt<<<2048, 256, 0, stream>>>(h_w, hw_h, 524288);

  // out = x + u * (silu(hx + hr @ h_w^T + h_b) - x)  (pipelined, nt=32)
  k_gemm_p3<4><<<dim3(8, 128, 1), 256, 0, stream>>>(rbuf, hw_h, 2048, 2048, 2048,
      h_b, d_out, nullptr, nullptr, nullptr, nullptr, (const void*)x);
}

// Round 15
// 1453.794 us; speedup vs baseline: 1.0762x; 1.0762x over previous
//
#include <hip/hip_runtime.h>
#include <cstdint>
#include <cstddef>

typedef __bf16 bf16;
typedef __bf16 bf16x8 __attribute__((ext_vector_type(8)));
typedef float  f32x4  __attribute__((ext_vector_type(4)));

#define DEVI static __device__ __forceinline__

DEVI float fsigmoid(float x) { return 1.0f / (1.0f + __expf(-x)); }
DEVI float fsilu(float x)    { return x / (1.0f + __expf(-x)); }

DEVI unsigned short b16bits(float v) { bf16 h = (bf16)v; return __builtin_bit_cast(unsigned short, h); }
DEVI float lo16f(unsigned int w) { return __builtin_bit_cast(float, w << 16); }
DEVI float hi16f(unsigned int w) { return __builtin_bit_cast(float, w & 0xffff0000u); }

DEVI float waveRedSum(float v) {
#pragma unroll
  for (int o = 32; o > 0; o >>= 1) v += __shfl_xor(v, o, 64);
  return v;
}
DEVI float waveRedMax(float v) {
#pragma unroll
  for (int o = 32; o > 0; o >>= 1) v = fmaxf(v, __shfl_xor(v, o, 64));
  return v;
}

// T1: bijective XCD-aware block swizzle (m204).
DEVI void xcd_swizzle(int& bx, int& by) {
  const int gx = gridDim.x, gy = gridDim.y;
  const int nwg = gx * gy;
  const int flat = blockIdx.y * gx + blockIdx.x;
  const int xcd = flat & 7;
  const int rem = nwg & 7;
  const int q = nwg >> 3;
  const int base = (xcd < rem) ? xcd * (q + 1) : rem * (q + 1) + (xcd - rem) * q;
  const int swz = base + (flat >> 3);
  bx = swz % gx;
  by = swz / gx;
}

struct alignas(8) B4 { bf16 x, y, z, w; };

// ---------------- diagnostic fallback ----------------
__global__ __launch_bounds__(256) void k_copyout(const float* __restrict__ x, float* __restrict__ o)
{
  const long i = (long)blockIdx.x * 256 + threadIdx.x;
  ((float4*)o)[i] = ((const float4*)x)[i];
}

// ---------------- LN stats ----------------
__global__ __launch_bounds__(256) void k_lnstats(const float* __restrict__ x, float* __restrict__ stats)
{
  const long t = blockIdx.x;
  const int tid = threadIdx.x;
  const float4 v = ((const float4*)(x + t * 1024))[tid];
  float s  = v.x + v.y + v.z + v.w;
  float s2 = v.x * v.x + v.y * v.y + v.z * v.z + v.w * v.w;
  __shared__ float red[2][4];
  s = waveRedSum(s);
  s2 = waveRedSum(s2);
  const int wv = tid >> 6, ln = tid & 63;
  if (ln == 0) { red[0][wv] = s; red[1][wv] = s2; }
  __syncthreads();
  if (tid == 0) {
    s  = red[0][0] + red[0][1] + red[0][2] + red[0][3];
    s2 = red[1][0] + red[1][1] + red[1][2] + red[1][3];
    const float mu  = s * (1.0f / 1024.0f);
    const float var = s2 * (1.0f / 1024.0f) - mu * mu;
    stats[2 * t]     = mu;
    stats[2 * t + 1] = rsqrtf(var + 1e-5f);
  }
}

// ---------------- f32 -> bf16 convert ----------------
__global__ __launch_bounds__(256) void k_cvt(const float* __restrict__ in, bf16* __restrict__ out, int n4)
{
  const int i = blockIdx.x * 256 + threadIdx.x;
  if (i >= n4) return;
  const float4 v = ((const float4*)in)[i];
  B4 h; h.x = (bf16)v.x; h.y = (bf16)v.y; h.z = (bf16)v.z; h.w = (bf16)v.w;
  ((B4*)out)[i] = h;
}

// ---------------- EMA coefficients ----------------
__global__ __launch_bounds__(256) void k_ema_coeff(
    const float* __restrict__ de, const float* __restrict__ al,
    const float* __restrict__ be, const float* __restrict__ ga,
    float* __restrict__ qv, float* __restrict__ cv)
{
  const int i = blockIdx.x * 256 + threadIdx.x;
  const int d = i >> 4, n = i & 15;
  const float p = 1.0f / (1.0f + expf(-de[i]));
  const float a = 1.0f / (1.0f + expf(-al[i]));
  qv[n * 1024 + d] = 1.0f - p * a;
  cv[n * 1024 + d] = p * be[i] * ga[i] * 0.25f;
}

// ---------------- EMA pass 1 ----------------
__global__ __launch_bounds__(256) void k_ema_scan1(
    const float* __restrict__ x, const float* __restrict__ stats,
    const float* __restrict__ lnw, const float* __restrict__ lnb,
    const float* __restrict__ qv, float* __restrict__ scan)
{
  const int d = blockIdx.x * 256 + threadIdx.x;
  const int b = blockIdx.y, c = blockIdx.z;
  float q[16], s[16];
#pragma unroll
  for (int n = 0; n < 16; ++n) { q[n] = qv[n * 1024 + d]; s[n] = 0.0f; }
  const float wd = lnw[d], bd = lnb[d];
  const float* xp = x + (long)b * 1024 + d;
  const int l0 = c * 128;
  for (int j0 = 0; j0 < 128; j0 += 8) {
    float xr[8]; float2 st[8];
#pragma unroll
    for (int i = 0; i < 8; ++i) {
      const int l = l0 + j0 + i;
      xr[i] = xp[(long)l * 8192];
      st[i] = ((const float2*)stats)[(long)l * 8 + b];
    }
#pragma unroll
    for (int i = 0; i < 8; ++i) {
      const float xv = (xr[i] - st[i].x) * st[i].y * wd + bd;
#pragma unroll
      for (int n = 0; n < 16; ++n) s[n] = fmaf(q[n], s[n], xv);
    }
  }
  float* sp = scan + ((((long)c * 8 + b) * 1024) + d) * 16;
#pragma unroll
  for (int n = 0; n < 16; ++n) sp[n] = s[n];
}

// ---------------- EMA pass 2 ----------------
__global__ __launch_bounds__(256) void k_ema_scan2(
    const float* __restrict__ qv, float* __restrict__ scan)
{
  const int i = blockIdx.x * 256 + threadIdx.x;
  const int n = i & 15, d = (i >> 4) & 1023, b = i >> 14;
  const float q = qv[n * 1024 + d];
  const float q2 = q * q, q4 = q2 * q2, q8 = q4 * q4;
  const float q16 = q8 * q8, q32 = q16 * q16, q64 = q32 * q32, q128 = q64 * q64;
  float carry = 0.0f;
#pragma unroll
  for (int c = 0; c < 16; ++c) {
    const long off = ((((long)c * 8 + b) * 1024) + d) * 16 + n;
    const float t = scan[off];
    scan[off] = carry;
    carry = fmaf(q128, carry, t);
  }
}

// ---------------- EMA pass 3 ----------------
__global__ __launch_bounds__(256) void k_ema_apply(
    const float* __restrict__ x, const float* __restrict__ stats,
    const float* __restrict__ lnw, const float* __restrict__ lnb,
    const float* __restrict__ qv, const float* __restrict__ cv,
    const float* __restrict__ omega, const float* __restrict__ scan,
    bf16* __restrict__ mx)
{
  const int d = blockIdx.x * 256 + threadIdx.x;
  const int b = blockIdx.y, c = blockIdx.z;
  float q[16], cc[16], s[16];
  const float* sp = scan + ((((long)c * 8 + b) * 1024) + d) * 16;
#pragma unroll
  for (int n = 0; n < 16; ++n) {
    q[n] = qv[n * 1024 + d];
    cc[n] = cv[n * 1024 + d];
    s[n] = sp[n];
  }
  const float om = omega[d], wd = lnw[d], bd = lnb[d];
  const float* xp = x + (long)b * 1024 + d;
  bf16* mp = mx + (long)b * 1024 + d;
  const int l0 = c * 128;
  for (int j0 = 0; j0 < 128; j0 += 8) {
    float xr[8]; float2 st[8];
#pragma unroll
    for (int i = 0; i < 8; ++i) {
      const int l = l0 + j0 + i;
      xr[i] = xp[(long)l * 8192];
      st[i] = ((const float2*)stats)[(long)l * 8 + b];
    }
#pragma unroll
    for (int i = 0; i < 8; ++i) {
      const float xv = (xr[i] - st[i].x) * st[i].y * wd + bd;
      float p0 = 0.f, p1 = 0.f, p2 = 0.f, p3 = 0.f;
#pragma unroll
      for (int n = 0; n < 16; n += 4) {
        s[n]     = fmaf(q[n],     s[n],     xv);
        s[n + 1] = fmaf(q[n + 1], s[n + 1], xv);
        s[n + 2] = fmaf(q[n + 2], s[n + 2], xv);
        s[n + 3] = fmaf(q[n + 3], s[n + 3], xv);
        p0 = fmaf(cc[n],     s[n],     p0);
        p1 = fmaf(cc[n + 1], s[n + 1], p1);
        p2 = fmaf(cc[n + 2], s[n + 2], p2);
        p3 = fmaf(cc[n + 3], s[n + 3], p3);
      }
      const float pre = fmaf(xv, om, (p0 + p1) + (p2 + p3));
      mp[(long)(l0 + j0 + i) * 8192] = (bf16)fsilu(pre);
    }
  }
}

// ---------------- rotary columns ----------------
__global__ __launch_bounds__(64) void k_rotfill(
    const float* __restrict__ rba, const float* __restrict__ rbb,
    bf16* __restrict__ Qp, bf16* __restrict__ Kp)
{
  const int l = blockIdx.x, zi = threadIdx.x;
  const float fr = __expf(-0.14391156831212787f * (float)zi);
  const float pos = (float)l * fr;
  const float sn = sinf(pos), cs = cosf(pos);
  const float a1 = rba[zi], a2 = rba[64 + zi];
  const float b1 = rbb[zi], b2 = rbb[64 + zi];
  const bf16 qa = (bf16)(a1 * cs - a2 * sn);
  const bf16 qb = (bf16)(a2 * cs + a1 * sn);
  const bf16 ka = (bf16)(b1 * cs - b2 * sn);
  const bf16 kb = (bf16)(b2 * cs + b1 * sn);
#pragma unroll
  for (int b = 0; b < 8; ++b) {
    const long base = ((long)b * 2048 + l) * 256;
    Qp[base + 128 + zi] = qa;
    Qp[base + 192 + zi] = qb;
    Kp[base + 128 + zi] = ka;
    Kp[base + 192 + zi] = kb;
  }
}

// ------- row softmax IN-PLACE on bf16 S: row (2048 bf16) -> P bf16 same place -------
// Each thread reads/writes ONLY its own 8 contiguous elements (bf16x8) -> race-free.
__global__ __launch_bounds__(256) void k_softmax(bf16* __restrict__ S)
{
  const long row = blockIdx.x;
  bf16* sp = S + row * 2048;
  const int tid = threadIdx.x;
  const bf16x8 v = *(const bf16x8*)&sp[tid * 8];
  float vals[8];
  float mx = -1e30f;
#pragma unroll
  for (int i = 0; i < 8; ++i) { vals[i] = (float)v[i]; mx = fmaxf(mx, vals[i]); }
  __shared__ float red[4];
  mx = waveRedMax(mx);
  const int wv = tid >> 6, ln = tid & 63;
  if (ln == 0) red[wv] = mx;
  __syncthreads();
  mx = fmaxf(fmaxf(red[0], red[1]), fmaxf(red[2], red[3]));
  float sum = 0.f;
#pragma unroll
  for (int i = 0; i < 8; ++i) { vals[i] = __expf(vals[i] - mx); sum += vals[i]; }
  __syncthreads();
  sum = waveRedSum(sum);
  if (ln == 0) red[wv] = sum;
  __syncthreads();
  sum = red[0] + red[1] + red[2] + red[3];
  const float inv = 1.0f / sum;
  bf16x8 o;
#pragma unroll
  for (int i = 0; i < 8; ++i) o[i] = (bf16)(vals[i] * inv);
  *(bf16x8*)&sp[tid * 8] = o;
}

// ------- V transpose (one M-slice): vbufe (2048 t-rows, 2048 h) -> v_t (b, h, loff+l) -------
__global__ __launch_bounds__(1024) void k_vtrans8(
    const bf16* __restrict__ v, bf16* __restrict__ vt, const int loff)
{
  __shared__ bf16 tile[32][33];
  const int l0 = blockIdx.x * 32, h0 = blockIdx.y * 32, b = blockIdx.z;
  const int tx = threadIdx.x, ty = threadIdx.y;
  tile[ty][tx] = v[((long)(l0 + ty) * 8 + b) * 2048 + h0 + tx];
  __syncthreads();
  vt[((long)b * 2048 + h0 + ty) * 2048 + loff + l0 + tx] = tile[tx][ty];
}

DEVI void gload16(const void* g, void* l) {
  __builtin_amdgcn_global_load_lds(
      (__attribute__((address_space(1))) void*)(void*)g,
      (__attribute__((address_space(3))) void*)l, 16, 0, 0);
}

// ---------------- 128x128 2-barrier NT GEMM (T1 + T2) — the proven structure ----------------
// EPI: 1 = base proj split epilogue; 2 = bf16 scores (o0, ld 2048);
//      3 = PV (*r in-place, row remap); 4 = final
template<int EPI>
__global__ __launch_bounds__(256) void k_gemm_bt(
    const bf16* __restrict__ A, const bf16* __restrict__ Bm,
    const int K, const int lda, const int ldb, const int coladd,
    const float* __restrict__ bias,
    void* __restrict__ o0, void* __restrict__ o1, void* __restrict__ o2, void* __restrict__ o3,
    const void* __restrict__ e0, const void* __restrict__ e1, const void* __restrict__ e2)
{
  __shared__ alignas(16) bf16 As[128 * 64];
  __shared__ alignas(16) bf16 Bs[128 * 64];
  const int tid = threadIdx.x;
  const int wave = tid >> 6, lane = tid & 63;
  const int wm = wave >> 1, wn = wave & 1;
  int bx, by;
  xcd_swizzle(bx, by);
  const int tm = by * 128, tn = bx * 128;
  const int fr = lane & 15, kg = lane >> 4;

  f32x4 acc[4][4];
  const f32x4 z4 = {0.0f, 0.0f, 0.0f, 0.0f};
#pragma unroll
  for (int i = 0; i < 4; ++i)
#pragma unroll
    for (int j = 0; j < 4; ++j) acc[i][j] = z4;

  const int srow = wave * 8 + (lane >> 3);
  const int scol = ((lane & 7) ^ (lane >> 3)) * 8;   // T2 pre-swizzled source chunk
  const long arow = (long)(tm + srow);
  const long brow = (long)(tn + srow);
  const int swR = (fr & 7) << 3;                     // read-side XOR

  for (int k0 = 0; k0 < K; k0 += 64) {
    __syncthreads();
#pragma unroll
    for (int cc = 0; cc < 4; ++cc) {
      gload16(A + (arow + cc * 32) * lda + k0 + scol, As + cc * 2048 + wave * 512);
      gload16(Bm + (brow + cc * 32) * ldb + k0 + scol, Bs + cc * 2048 + wave * 512);
    }
    __syncthreads();
    bf16x8 af[2][4], bfv[2][4];
#pragma unroll
    for (int ks = 0; ks < 2; ++ks)
#pragma unroll
      for (int i = 0; i < 4; ++i) {
        af[ks][i]  = *(const bf16x8*)&As[(wm * 64 + i * 16 + fr) * 64 + ((ks * 32 + kg * 8) ^ swR)];
        bfv[ks][i] = *(const bf16x8*)&Bs[(wn * 64 + i * 16 + fr) * 64 + ((ks * 32 + kg * 8) ^ swR)];
      }
#pragma unroll
    for (int ks = 0; ks < 2; ++ks)
#pragma unroll
      for (int i = 0; i < 4; ++i)
#pragma unroll
        for (int j = 0; j < 4; ++j)
          acc[i][j] = __builtin_amdgcn_mfma_f32_16x16x32_bf16(af[ks][i], bfv[ks][j], acc[i][j], 0, 0, 0);
  }

#pragma unroll
  for (int i = 0; i < 4; ++i) {
#pragma unroll
    for (int j = 0; j < 4; ++j) {
#pragma unroll
      for (int rr = 0; rr < 4; ++rr) {
        const int row = tm + wm * 64 + i * 16 + kg * 4 + rr;
        const int col = coladd + tn + wn * 64 + j * 16 + fr;
        const float a = acc[i][j][rr];
        if constexpr (EPI == 1) {
          const float tv = a + bias[col];
          if (col < 1024) {
            ((unsigned short*)o0)[((long)row * 1024 + col) * 2] = b16bits(fsigmoid(tv));
          } else if (col < 1152) {
            const int zi = col - 1024;
            const float zval = fsilu(tv);
            const float qq = (zval * ((const float*)e0)[zi] + ((const float*)e1)[zi]) * 0.08838834764831845f;
            const float kk =  zval * ((const float*)e0)[128 + zi] + ((const float*)e1)[128 + zi];
            const long base = ((long)(row & 7) * 2048 + (row >> 3)) * 256 + zi;
            ((bf16*)o2)[base] = (bf16)qq;
            ((bf16*)o3)[base] = (bf16)kk;
          } else if (col < 3200) {
            ((bf16*)o1)[(long)row * 2048 + (col - 1152)] = (bf16)fsilu(tv);
          } else {
            ((unsigned short*)o0)[((long)row * 1024 + (col - 3200)) * 2 + 1] = b16bits(tv);
          }
        } else if constexpr (EPI == 2) {
          ((bf16*)o0)[(long)row * 2048 + col] = (bf16)a;
        } else if constexpr (EPI == 3) {
          const long idx = (long)row * 16384 + col;   // (row*8)*2048 + col
          const float rv = (float)((const bf16*)e0)[idx];
          ((bf16*)o0)[idx] = (bf16)(a * rv);
        } else if constexpr (EPI == 4) {
          const long idx = (long)row * 1024 + col;
          const unsigned int w = ((const unsigned int*)o0)[idx];
          const float uv = lo16f(w), hxv = hi16f(w);
          const float hval = fsilu(hxv + a + bias[col]);
          const float xv = ((const float*)e1)[idx];
          ((float*)o0)[idx] = xv + uv * (hval - xv);
        }
      }
    }
  }
}

// ---------------- V-proj GEMM with fused-LN A staging ----------------
__global__ __launch_bounds__(256) void k_gemm_lnA(
    const float* __restrict__ x, const float* __restrict__ stats,
    const float* __restrict__ lnw, const float* __restrict__ lnb,
    const bf16* __restrict__ Bm, const float* __restrict__ bias,
    bf16* __restrict__ out)
{
  __shared__ alignas(16) bf16 As[128 * 64];
  __shared__ alignas(16) bf16 Bs[128 * 64];
  __shared__ float smu[128], srs[128];
  const int tid = threadIdx.x;
  const int wave = tid >> 6, lane = tid & 63;
  const int wm = wave >> 1, wn = wave & 1;
  int bx, by;
  xcd_swizzle(bx, by);
  const int tm = by * 128, tn = bx * 128;
  const int fr = lane & 15, kg = lane >> 4;
  if (tid < 128) {
    smu[tid] = stats[2 * (long)(tm + tid)];
    srs[tid] = stats[2 * (long)(tm + tid) + 1];
  }

  f32x4 acc[4][4];
  const f32x4 z4 = {0.0f, 0.0f, 0.0f, 0.0f};
#pragma unroll
  for (int i = 0; i < 4; ++i)
#pragma unroll
    for (int j = 0; j < 4; ++j) acc[i][j] = z4;

  const int srow = wave * 8 + (lane >> 3);
  const int scol = ((lane & 7) ^ (lane >> 3)) * 8;
  const long brow = (long)(tn + srow);
  const int swR = (fr & 7) << 3;
  const int ar = tid & 127, ah = (tid >> 7) * 32;
  const float* xrow = x + (long)(tm + ar) * 1024 + ah;

  for (int k0 = 0; k0 < 1024; k0 += 64) {
    __syncthreads();
#pragma unroll
    for (int cc = 0; cc < 4; ++cc)
      gload16(Bm + (brow + cc * 32) * 1024 + k0 + scol, Bs + cc * 2048 + wave * 512);
    {
      const float mu = smu[ar], rs = srs[ar];
      bf16 tmp[32];
#pragma unroll
      for (int i = 0; i < 8; ++i) {
        const float4 xv = ((const float4*)(xrow + k0))[i];
        const float4 wv = ((const float4*)(lnw + k0 + ah))[i];
        const float4 bv = ((const float4*)(lnb + k0 + ah))[i];
        tmp[i * 4 + 0] = (bf16)((xv.x - mu) * rs * wv.x + bv.x);
        tmp[i * 4 + 1] = (bf16)((xv.y - mu) * rs * wv.y + bv.y);
        tmp[i * 4 + 2] = (bf16)((xv.z - mu) * rs * wv.z + bv.z);
        tmp[i * 4 + 3] = (bf16)((xv.w - mu) * rs * wv.w + bv.w);
      }
      const int sw = (ar & 7) << 3;
#pragma unroll
      for (int i = 0; i < 4; ++i)
        *(bf16x8*)&As[ar * 64 + ((ah + i * 8) ^ sw)] = *(const bf16x8*)&tmp[i * 8];
    }
    __syncthreads();
    bf16x8 af[2][4], bfv[2][4];
#pragma unroll
    for (int ks = 0; ks < 2; ++ks)
#pragma unroll
      for (int i = 0; i < 4; ++i) {
        const int ar2 = wm * 64 + i * 16 + fr;
        af[ks][i]  = *(const bf16x8*)&As[ar2 * 64 + ((ks * 32 + kg * 8) ^ ((ar2 & 7) << 3))];
        bfv[ks][i] = *(const bf16x8*)&Bs[(wn * 64 + i * 16 + fr) * 64 + ((ks * 32 + kg * 8) ^ swR)];
      }
#pragma unroll
    for (int ks = 0; ks < 2; ++ks)
#pragma unroll
      for (int i = 0; i < 4; ++i)
#pragma unroll
        for (int j = 0; j < 4; ++j)
          acc[i][j] = __builtin_amdgcn_mfma_f32_16x16x32_bf16(af[ks][i], bfv[ks][j], acc[i][j], 0, 0, 0);
  }

#pragma unroll
  for (int i = 0; i < 4; ++i)
#pragma unroll
    for (int j = 0; j < 4; ++j)
#pragma unroll
      for (int rr = 0; rr < 4; ++rr) {
        const int row = tm + wm * 64 + i * 16 + kg * 4 + rr;
        const int col = tn + wn * 64 + j * 16 + fr;
        out[(long)row * 2048 + col] = (bf16)fsilu(acc[i][j][rr] + bias[col]);
      }
}

extern "C" void kernel_launch(void* const* d_in, const int* in_sizes, int n_in,
                              void* d_out, int out_size, void* d_ws, size_t ws_size,
                              hipStream_t stream)
{
  const float* x    = (const float*)d_in[0];
  const float* ln_w = (const float*)d_in[1];
  const float* ln_b = (const float*)d_in[2];
  const float* v_w  = (const float*)d_in[3];
  const float* v_b  = (const float*)d_in[4];
  const float* mx_w = (const float*)d_in[5];
  const float* mx_b = (const float*)d_in[6];
  const float* h_w  = (const float*)d_in[7];
  const float* h_b  = (const float*)d_in[8];
  const float* qk_g = (const float*)d_in[9];
  const float* qk_b = (const float*)d_in[10];
  const float* e_de = (const float*)d_in[11];
  const float* e_al = (const float*)d_in[12];
  const float* e_be = (const float*)d_in[13];
  const float* e_ga = (const float*)d_in[14];
  const float* e_om = (const float*)d_in[15];
  const float* rb_a = (const float*)d_in[16];
  const float* rb_b = (const float*)d_in[17];

  const size_t MiB = 1048576UL;
  if (ws_size < 160 * MiB) {
    k_copyout<<<16384, 256, 0, stream>>>(x, (float*)d_out);
    return;
  }

  // Static map, peak 160 MiB (Sbuf now bf16, 8 MiB):
  char* ws = (char*)d_ws;
  bf16*  rbuf  = (bf16*)(ws + 0 * MiB);
  bf16*  v_t   = (bf16*)(ws + 64 * MiB);
  bf16*  mxw_h = (bf16*)(ws + 64 * MiB);
  bf16*  mxb   = (bf16*)(ws + 73 * MiB);
  float* qv    = (float*)(ws + 105 * MiB);
  float* cv    = (float*)(ws + 105 * MiB + 65536);
  bf16*  Qp    = (bf16*)(ws + 128 * MiB);
  bf16*  hw_h  = (bf16*)(ws + 128 * MiB);
  bf16*  Kp    = (bf16*)(ws + 136 * MiB);
  bf16*  Sbuf  = (bf16*)(ws + 144 * MiB);
  bf16*  vw_h  = (bf16*)(ws + 144 * MiB);
  float* scanb = (float*)(ws + 148 * MiB);
  bf16*  vbufe = (bf16*)(ws + 148 * MiB);
  float* stats = (float*)(ws + 156 * MiB);

  k_lnstats<<<16384, 256, 0, stream>>>(x, stats);
  k_cvt<<<2048, 256, 0, stream>>>(v_w, vw_h, 524288);
  k_cvt<<<4224, 256, 0, stream>>>(mx_w, mxw_h, 1081344);
  k_ema_coeff<<<64, 256, 0, stream>>>(e_de, e_al, e_be, e_ga, qv, cv);

  // EMA via 3-pass chunked parallel scan
  k_ema_scan1<<<dim3(4, 8, 16), 256, 0, stream>>>(x, stats, ln_w, ln_b, qv, scanb);
  k_ema_scan2<<<512, 256, 0, stream>>>(qv, scanb);
  k_ema_apply<<<dim3(4, 8, 16), 256, 0, stream>>>(x, stats, ln_w, ln_b, qv, cv, e_om, scanb, mxb);

  // base = mx @ mx_w^T + mx_b (2-barrier 128^2, the proven structure):
  // u -> d_out.lo16, z -> Qp/Kp, r -> rbuf, hx -> d_out.hi16
  k_gemm_bt<1><<<dim3(33, 128, 1), 256, 0, stream>>>(mxb, mxw_h, 1024, 1024, 1024, 0,
      mx_b, d_out, (void*)rbuf, (void*)Qp, (void*)Kp, (const void*)qk_g, (const void*)qk_b, nullptr);
  k_rotfill<<<2048, 64, 0, stream>>>(rb_a, rb_b, Qp, Kp);

  // V-proj in 8 M-slices, each transposed into v_t at l-offset e*256
  for (int e = 0; e < 8; ++e) {
    k_gemm_lnA<<<dim3(16, 16, 1), 256, 0, stream>>>(x + (long)e * 2048 * 1024, stats + (long)e * 4096,
        ln_w, ln_b, vw_h, v_b, vbufe);
    k_vtrans8<<<dim3(8, 64, 8), dim3(32, 32), 0, stream>>>(vbufe, v_t, e * 256);
  }

  // attention per full batch: QK (bf16 S) -> softmax (in-place) -> PV
  for (int b = 0; b < 8; ++b) {
    const bf16* Ab = Qp + (long)b * 524288;
    const bf16* Bb = Kp + (long)b * 524288;
    k_gemm_bt<2><<<dim3(16, 16, 1), 256, 0, stream>>>(Ab, Bb, 256, 256, 256, 0,
        nullptr, (void*)Sbuf, nullptr, nullptr, nullptr, nullptr, nullptr, nullptr);
    k_softmax<<<2048, 256, 0, stream>>>(Sbuf);
    bf16* hrp = rbuf + (long)b * 2048;
    k_gemm_bt<3><<<dim3(16, 16, 1), 256, 0, stream>>>((const bf16*)Sbuf, v_t + (long)b * 4194304,
        2048, 2048, 2048, 0, nullptr, (void*)hrp, nullptr, nullptr, nullptr, (const void*)hrp, nullptr, nullptr);
  }

  // h_w -> bf16 into dead Qp slot
  k_cvt<<<2048, 256, 0, stream>>>(h_w, hw_h, 524288);

  // out = x + u * (silu(hx + hr @ h_w^T + h_b) - x)
  k_gemm_bt<4><<<dim3(8, 128, 1), 256, 0, stream>>>(rbuf, hw_h, 2048, 2048, 2048, 0,
      h_b, d_out, nullptr, nullptr, nullptr, nullptr, (const void*)x, nullptr);
}